// Round 5
// baseline (1039.265 us; speedup 1.0000x reference)
//
#include <hip/hip_runtime.h>
#include <stdint.h>

typedef unsigned short u16;
typedef __bf16 bf16x8 __attribute__((ext_vector_type(8)));
typedef float f32x4 __attribute__((ext_vector_type(4)));

#define LOG2E 1.4426950408889634f

__device__ __forceinline__ float bf2f(u16 a) {
  union { unsigned u; float f; } v; v.u = ((unsigned)a) << 16; return v.f;
}
__device__ __forceinline__ u16 f2bf(float f) {
  union { float f; unsigned u; } v; v.f = f;
  unsigned r = v.u + 0x7fffu + ((v.u >> 16) & 1u);
  return (u16)(r >> 16);
}

// ---------------------------------------------------------------------------
// GEMM: acc = A[M,K] @ Bt[N,K]^T  (A,Bt bf16 in ws; fp32 accum)
// Plain VGPR-mediated staging. BK=32, 4 waves 2x2, mfma 16x16x32 bf16.
// Epilogue MODE: 0 = bf16 C=acc
//               1 = bf16 C=acc+bias+bf2f(resbf)        (o-proj, C may==resbf)
//               2 = bf16 C=relu(acc+bias)              (FFN1)
//               3 = f32  C32=acc+bias+resx+bf2f(resbf) (FFN2 band0)
//               4 = f32  C32+=acc                      (FFN2 band1)
// ---------------------------------------------------------------------------
template <int BM, int BN, int MODE>
__global__ __launch_bounds__(256) void gemm_bt(
    const u16* __restrict__ A, const u16* __restrict__ Bt,
    u16* Cbf, float* C32,
    const float* __restrict__ bias,
    const u16* resbf, const float* __restrict__ resx,
    int M, int N, int K)
{
  constexpr int MT = BM / 32, NT = BN / 32;
  constexpr int GA = (BM * 4) / 256, GB = (BN * 4) / 256;
  __shared__ u16 sA[BM * 32];
  __shared__ u16 sB[BN * 32];
  const int tid  = threadIdx.x;
  const int wave = tid >> 6, lane = tid & 63;
  const int quad = lane >> 4, l16 = lane & 15;
  const int wm = wave >> 1, wn = wave & 1;
  const int m0 = blockIdx.y * BM, n0 = blockIdx.x * BN;

  f32x4 acc[MT][NT] = {};

  for (int k0 = 0; k0 < K; k0 += 32) {
    uint4 av[GA], bv[GB];
#pragma unroll
    for (int i = 0; i < GA; ++i) {
      int g = i * 256 + tid, row = g >> 2, kc = g & 3;
      av[i] = *(const uint4*)&A[(size_t)(m0 + row) * K + k0 + kc * 8];
    }
#pragma unroll
    for (int i = 0; i < GB; ++i) {
      int g = i * 256 + tid, row = g >> 2, kc = g & 3;
      bv[i] = *(const uint4*)&Bt[(size_t)(n0 + row) * K + k0 + kc * 8];
    }
    __syncthreads();  // previous tile's LDS reads done
#pragma unroll
    for (int i = 0; i < GA; ++i) { int g = i * 256 + tid; *(uint4*)&sA[g * 8] = av[i]; }
#pragma unroll
    for (int i = 0; i < GB; ++i) { int g = i * 256 + tid; *(uint4*)&sB[g * 8] = bv[i]; }
    __syncthreads();  // staging visible

    bf16x8 fa[MT], fb[NT];
#pragma unroll
    for (int mt = 0; mt < MT; ++mt)
      fa[mt] = *(const bf16x8*)&sA[(wm * (BM / 2) + mt * 16 + l16) * 32 + quad * 8];
#pragma unroll
    for (int nt = 0; nt < NT; ++nt)
      fb[nt] = *(const bf16x8*)&sB[(wn * (BN / 2) + nt * 16 + l16) * 32 + quad * 8];
#pragma unroll
    for (int mt = 0; mt < MT; ++mt)
#pragma unroll
      for (int nt = 0; nt < NT; ++nt)
        acc[mt][nt] = __builtin_amdgcn_mfma_f32_16x16x32_bf16(
            fa[mt], fb[nt], acc[mt][nt], 0, 0, 0);
  }

  // epilogue: C layout col=lane&15, row=quad*4+reg
#pragma unroll
  for (int mt = 0; mt < MT; ++mt) {
#pragma unroll
    for (int nt = 0; nt < NT; ++nt) {
#pragma unroll
      for (int r = 0; r < 4; ++r) {
        int row = m0 + wm * (BM / 2) + mt * 16 + quad * 4 + r;
        int col = n0 + wn * (BN / 2) + nt * 16 + l16;
        size_t idx = (size_t)row * N + col;
        float v = acc[mt][nt][r];
        if constexpr (MODE == 0) {
          Cbf[idx] = f2bf(v);
        } else if constexpr (MODE == 1) {
          v += bias[col] + bf2f(resbf[idx]);
          Cbf[idx] = f2bf(v);
        } else if constexpr (MODE == 2) {
          v = fmaxf(v + bias[col], 0.f);
          Cbf[idx] = f2bf(v);
        } else if constexpr (MODE == 3) {
          v += bias[col] + resx[idx] + bf2f(resbf[idx]);
          C32[idx] = v;
        } else {  // MODE 4
          C32[idx] = C32[idx] + v;
        }
      }
    }
  }
}

// ---------------------------------------------------------------------------
// 64x64-tiled transpose + fp32->bf16 cast: out[c][r] = (bf16)in[r][c].
// in fp32 row stride Cstride; out bf16 row stride R.
// ---------------------------------------------------------------------------
__global__ __launch_bounds__(256) void transpose64(
    const float* __restrict__ in, u16* __restrict__ out, int R, int Cstride)
{
  __shared__ u16 tile[64][72];
  const int r0 = blockIdx.y * 64, c0 = blockIdx.x * 64;
  const int t = threadIdx.x;
  // load 64x64 fp32, cast to bf16 into LDS: 4 passes of 256 float4
  {
    const int lr = t >> 4, lc = (t & 15) * 4;
#pragma unroll
    for (int h = 0; h < 4; ++h) {
      int row = h * 16 + lr;
      float4 vd = *(const float4*)&in[(size_t)(r0 + row) * Cstride + c0 + lc];
      ushort4 ov;
      ov.x = f2bf(vd.x); ov.y = f2bf(vd.y); ov.z = f2bf(vd.z); ov.w = f2bf(vd.w);
      *(ushort4*)&tile[row][lc] = ov;
    }
  }
  __syncthreads();
  {
    const int lr = t >> 3, lv = t & 7;
#pragma unroll
    for (int h = 0; h < 2; ++h) {
      int orow = h * 32 + lr;
      u16 tmp[8];
#pragma unroll
      for (int j = 0; j < 8; ++j) tmp[j] = tile[lv * 8 + j][orow];
      *(uint4*)&out[(size_t)(c0 + orow) * R + r0 + lv * 8] = *(uint4*)tmp;
    }
  }
}

// ---------------------------------------------------------------------------
// LayerNorm over D=1024, fp32 in -> bf16 out. One block per row.
// ---------------------------------------------------------------------------
__global__ __launch_bounds__(256) void ln_kernel(
    const float* __restrict__ x, const float* __restrict__ g,
    const float* __restrict__ b, u16* __restrict__ outbf)
{
  const int row = blockIdx.x, t = threadIdx.x;
  const int wave = t >> 6, lane = t & 63;
  float4 xv = *(const float4*)&x[(size_t)row * 1024 + t * 4];
  float v0 = xv.x, v1 = xv.y, v2 = xv.z, v3 = xv.w;
  float s = v0 + v1 + v2 + v3;
  float s2 = v0 * v0 + v1 * v1 + v2 * v2 + v3 * v3;
  for (int m = 1; m < 64; m <<= 1) { s += __shfl_xor(s, m); s2 += __shfl_xor(s2, m); }
  __shared__ float ps[4], pq[4];
  if (lane == 0) { ps[wave] = s; pq[wave] = s2; }
  __syncthreads();
  s = ps[0] + ps[1] + ps[2] + ps[3];
  s2 = pq[0] + pq[1] + pq[2] + pq[3];
  float mean = s * (1.f / 1024.f);
  float var = s2 * (1.f / 1024.f) - mean * mean;
  float rs = rsqrtf(var + 1e-5f);
  float4 gv = *(const float4*)&g[t * 4];
  float4 bv = *(const float4*)&b[t * 4];
  ushort4 ov;
  ov.x = f2bf((v0 - mean) * rs * gv.x + bv.x);
  ov.y = f2bf((v1 - mean) * rs * gv.y + bv.y);
  ov.z = f2bf((v2 - mean) * rs * gv.z + bv.z);
  ov.w = f2bf((v3 - mean) * rs * gv.w + bv.w);
  *(ushort4*)&outbf[(size_t)row * 1024 + t * 4] = ov;
}

// h = LN(x + y) where x fp32, y bf16. No x2 materialization (final GEMM
// recomputes x+y in its epilogue).
__global__ __launch_bounds__(256) void ln_add_kernel(
    const float* __restrict__ x, const u16* __restrict__ ybf,
    const float* __restrict__ g, const float* __restrict__ b,
    u16* __restrict__ hbf)
{
  const int row = blockIdx.x, t = threadIdx.x;
  const int wave = t >> 6, lane = t & 63;
  float4 xv = *(const float4*)&x[(size_t)row * 1024 + t * 4];
  ushort4 yv = *(const ushort4*)&ybf[(size_t)row * 1024 + t * 4];
  float v0 = xv.x + bf2f(yv.x), v1 = xv.y + bf2f(yv.y);
  float v2 = xv.z + bf2f(yv.z), v3 = xv.w + bf2f(yv.w);
  float s = v0 + v1 + v2 + v3;
  float s2 = v0 * v0 + v1 * v1 + v2 * v2 + v3 * v3;
  for (int m = 1; m < 64; m <<= 1) { s += __shfl_xor(s, m); s2 += __shfl_xor(s2, m); }
  __shared__ float ps[4], pq[4];
  if (lane == 0) { ps[wave] = s; pq[wave] = s2; }
  __syncthreads();
  s = ps[0] + ps[1] + ps[2] + ps[3];
  s2 = pq[0] + pq[1] + pq[2] + pq[3];
  float mean = s * (1.f / 1024.f);
  float var = s2 * (1.f / 1024.f) - mean * mean;
  float rs = rsqrtf(var + 1e-5f);
  float4 gv = *(const float4*)&g[t * 4];
  float4 bv = *(const float4*)&b[t * 4];
  ushort4 ov;
  ov.x = f2bf((v0 - mean) * rs * gv.x + bv.x);
  ov.y = f2bf((v1 - mean) * rs * gv.y + bv.y);
  ov.z = f2bf((v2 - mean) * rs * gv.z + bv.z);
  ov.w = f2bf((v3 - mean) * rs * gv.w + bv.w);
  *(ushort4*)&hbf[(size_t)row * 1024 + t * 4] = ov;
}

// ---------------------------------------------------------------------------
// Flash-style cross-attention, all-bf16 buffers. Block = (64-q-tile, head, b).
// Wave w owns q-rows [w*16, w*16+16). Online softmax, P via LDS round-trip.
// ---------------------------------------------------------------------------
__global__ __launch_bounds__(256) void attn_kernel(
    const u16* __restrict__ Q, const u16* __restrict__ K,
    const u16* __restrict__ V, const int* __restrict__ mask,
    u16* __restrict__ O)
{
  __shared__ u16 sQ[64 * 64], sK[64 * 64], sVt[64 * 64], sP[64 * 64];
  __shared__ int smaski[64];
  const int qt = blockIdx.x, h = blockIdx.y, b = blockIdx.z;
  const int t = threadIdx.x;
  const int wave = t >> 6, lane = t & 63;
  const int quad = lane >> 4, l16 = lane & 15;
  const int ld = 1024;
  const u16* Qb = Q + (size_t)b * 1024 * ld + (size_t)qt * 64 * ld + h * 64;
  const u16* Kb = K + (size_t)b * 1024 * ld + h * 64;
  const u16* Vb = V + (size_t)b * 1024 * ld + h * 64;

#pragma unroll
  for (int i = 0; i < 2; ++i) {
    int g = i * 256 + t, row = g >> 3, cc = g & 7;
    uint4 qv = *(const uint4*)&Qb[(size_t)row * ld + cc * 8];
    *(uint4*)&sQ[g * 8] = qv;
  }

  float m_[4], l_[4];
  f32x4 accO[4] = {};
#pragma unroll
  for (int r = 0; r < 4; ++r) { m_[r] = -1e30f; l_[r] = 0.f; }

  for (int j = 0; j < 16; ++j) {
    uint4 kvv[2], vv[2];
#pragma unroll
    for (int i = 0; i < 2; ++i) {
      int g = i * 256 + t, row = g >> 3, cc = g & 7;
      kvv[i] = *(const uint4*)&Kb[(size_t)(j * 64 + row) * ld + cc * 8];
    }
#pragma unroll
    for (int half = 0; half < 2; ++half) {
      int vr = half * 32 + (t >> 3), vc = t & 7;
      vv[half] = *(const uint4*)&Vb[(size_t)(j * 64 + vr) * ld + vc * 8];
    }
    int mv = (t < 64) ? mask[b * 1024 + j * 64 + t] : 0;
    __syncthreads();  // prev iter LDS reads done
#pragma unroll
    for (int i = 0; i < 2; ++i) { int g = i * 256 + t; *(uint4*)&sK[g * 8] = kvv[i]; }
#pragma unroll
    for (int half = 0; half < 2; ++half) {
      int vr = half * 32 + (t >> 3), vc = t & 7;
      u16 tmp[8]; *(uint4*)tmp = vv[half];
#pragma unroll
      for (int jj = 0; jj < 8; ++jj) sVt[(vc * 8 + jj) * 64 + vr] = tmp[jj];
    }
    if (t < 64) smaski[t] = mv;
    __syncthreads();  // sK/sVt/smaski ready

    f32x4 accS[4] = {};
#pragma unroll
    for (int ks = 0; ks < 2; ++ks) {
      bf16x8 aq = *(const bf16x8*)&sQ[(wave * 16 + l16) * 64 + ks * 32 + quad * 8];
#pragma unroll
      for (int nt = 0; nt < 4; ++nt) {
        bf16x8 bk = *(const bf16x8*)&sK[(nt * 16 + l16) * 64 + ks * 32 + quad * 8];
        accS[nt] = __builtin_amdgcn_mfma_f32_16x16x32_bf16(aq, bk, accS[nt], 0, 0, 0);
      }
    }
#pragma unroll
    for (int r = 0; r < 4; ++r) {
      float vals[4];
#pragma unroll
      for (int nt = 0; nt < 4; ++nt) {
        float sv = accS[nt][r] * 0.125f;
        vals[nt] = (smaski[nt * 16 + l16] == 0) ? -1e9f : sv;
      }
      float cm = fmaxf(fmaxf(vals[0], vals[1]), fmaxf(vals[2], vals[3]));
      for (int sh = 1; sh < 16; sh <<= 1) cm = fmaxf(cm, __shfl_xor(cm, sh));
      float nm = fmaxf(m_[r], cm);
      float alpha = exp2f((m_[r] - nm) * LOG2E);
      float rsum = 0.f;
#pragma unroll
      for (int nt = 0; nt < 4; ++nt) {
        float p = exp2f((vals[nt] - nm) * LOG2E);
        rsum += p;
        sP[(wave * 16 + quad * 4 + r) * 64 + nt * 16 + l16] = f2bf(p);
      }
      for (int sh = 1; sh < 16; sh <<= 1) rsum += __shfl_xor(rsum, sh);
      l_[r] = l_[r] * alpha + rsum;
      m_[r] = nm;
#pragma unroll
      for (int nt2 = 0; nt2 < 4; ++nt2) accO[nt2][r] *= alpha;
    }
    __syncthreads();  // sP ready
#pragma unroll
    for (int ks = 0; ks < 2; ++ks) {
      bf16x8 ap = *(const bf16x8*)&sP[(wave * 16 + l16) * 64 + ks * 32 + quad * 8];
#pragma unroll
      for (int nt2 = 0; nt2 < 4; ++nt2) {
        bf16x8 bvv = *(const bf16x8*)&sVt[(nt2 * 16 + l16) * 64 + ks * 32 + quad * 8];
        accO[nt2] = __builtin_amdgcn_mfma_f32_16x16x32_bf16(ap, bvv, accO[nt2], 0, 0, 0);
      }
    }
  }

  u16* Ob = O + (size_t)b * 1024 * ld + (size_t)qt * 64 * ld + h * 64;
#pragma unroll
  for (int r = 0; r < 4; ++r) {
    float inv = 1.f / l_[r];
    int row = wave * 16 + quad * 4 + r;
#pragma unroll
    for (int nt2 = 0; nt2 < 4; ++nt2)
      Ob[(size_t)row * ld + nt2 * 16 + l16] = f2bf(accO[nt2][r] * inv);
  }
}

// ---------------------------------------------------------------------------
extern "C" void kernel_launch(void* const* d_in, const int* in_sizes, int n_in,
                              void* d_out, int out_size, void* d_ws, size_t ws_size,
                              hipStream_t stream)
{
  const float* x   = (const float*)d_in[0];
  const float* kv  = (const float*)d_in[1];
  const int* attn_bias = (const int*)d_in[2];
  const float* ln1_g = (const float*)d_in[3];
  const float* ln1_b = (const float*)d_in[4];
  const float* qw0 = (const float*)d_in[5];
  const float* kw0 = (const float*)d_in[6];
  const float* vw0 = (const float*)d_in[7];
  const float* ow0 = (const float*)d_in[8];
  const float* ob0 = (const float*)d_in[9];
  const float* qw1 = (const float*)d_in[10];
  const float* kw1 = (const float*)d_in[11];
  const float* vw1 = (const float*)d_in[12];
  const float* ow1 = (const float*)d_in[13];
  const float* ob1 = (const float*)d_in[14];
  const float* ln2_g = (const float*)d_in[15];
  const float* ln2_b = (const float*)d_in[16];
  const float* w1 = (const float*)d_in[17];
  const float* b1 = (const float*)d_in[18];
  const float* w2 = (const float*)d_in[19];
  const float* b2 = (const float*)d_in[20];

  // ---- workspace: 48 MB peak, bf16 buffers, phase-aliased ----
  char* ws = (char*)d_ws;
  const size_t MB = 1u << 20;
  u16* wtA   = (u16*)(ws + 0 * MB);    // bf16 weight-T scratch (<=4MB)
  u16* wtB   = (u16*)(ws + 4 * MB);    // second FFN band scratch (4MB)
  u16* ybf   = (u16*)(ws + 8 * MB);    // residual y, bf16 (8MB)
  u16* kvnbf = (u16*)(ws + 16 * MB);   // LN1(kv) bf16 (8MB); later hbf
  u16* kbuf  = (u16*)(ws + 24 * MB);   // k bf16 (8MB)  [fbuf reuses 24..40]
  u16* vbuf  = (u16*)(ws + 32 * MB);   // v bf16 (8MB)
  u16* qbuf  = (u16*)(ws + 40 * MB);   // q bf16 (8MB)
  u16* hbf   = kvnbf;                  // alias (kvn dead after attn1)
  u16* fbuf  = kbuf;                   // [4096,2048] bf16 16MB over kbuf+vbuf
  u16* attnb = (u16*)d_out;            // d_out (fp32 16MB) as bf16 scratch 8MB
  float* out32 = (float*)d_out;

  const dim3 B256(256);
  const dim3 gT(16, 16);        // 1024x1024 transpose
  const dim3 gGemmN1k(8, 64);   // <64,128>  M=4096,N=1024
  const dim3 gAttn(16, 16, 4);

  // --- LN1 ---
  ln_kernel<<<4096, B256, 0, stream>>>(x,  ln1_g, ln1_b, ybf);
  ln_kernel<<<4096, B256, 0, stream>>>(kv, ln1_g, ln1_b, kvnbf);

  // --- attention 0: q/k/v projections (JIT fp32->bf16 weight transpose) ---
  transpose64<<<gT, B256, 0, stream>>>(qw0, wtA, 1024, 1024);
  gemm_bt<64, 128, 0><<<gGemmN1k, B256, 0, stream>>>(
      ybf, wtA, qbuf, nullptr, nullptr, nullptr, nullptr, 4096, 1024, 1024);
  transpose64<<<gT, B256, 0, stream>>>(kw0, wtA, 1024, 1024);
  gemm_bt<64, 128, 0><<<gGemmN1k, B256, 0, stream>>>(
      kvnbf, wtA, kbuf, nullptr, nullptr, nullptr, nullptr, 4096, 1024, 1024);
  transpose64<<<gT, B256, 0, stream>>>(vw0, wtA, 1024, 1024);
  gemm_bt<64, 128, 0><<<gGemmN1k, B256, 0, stream>>>(
      kvnbf, wtA, vbuf, nullptr, nullptr, nullptr, nullptr, 4096, 1024, 1024);

  attn_kernel<<<gAttn, B256, 0, stream>>>(qbuf, kbuf, vbuf, attn_bias, attnb);

  // y = attn_out @ ow0 + ob0 + y
  transpose64<<<gT, B256, 0, stream>>>(ow0, wtA, 1024, 1024);
  gemm_bt<64, 128, 1><<<gGemmN1k, B256, 0, stream>>>(
      attnb, wtA, ybf, nullptr, ob0, ybf, nullptr, 4096, 1024, 1024);

  // --- attention 1 ---
  transpose64<<<gT, B256, 0, stream>>>(qw1, wtA, 1024, 1024);
  gemm_bt<64, 128, 0><<<gGemmN1k, B256, 0, stream>>>(
      ybf, wtA, qbuf, nullptr, nullptr, nullptr, nullptr, 4096, 1024, 1024);
  transpose64<<<gT, B256, 0, stream>>>(kw1, wtA, 1024, 1024);
  gemm_bt<64, 128, 0><<<gGemmN1k, B256, 0, stream>>>(
      kvnbf, wtA, kbuf, nullptr, nullptr, nullptr, nullptr, 4096, 1024, 1024);
  transpose64<<<gT, B256, 0, stream>>>(vw1, wtA, 1024, 1024);
  gemm_bt<64, 128, 0><<<gGemmN1k, B256, 0, stream>>>(
      kvnbf, wtA, vbuf, nullptr, nullptr, nullptr, nullptr, 4096, 1024, 1024);

  attn_kernel<<<gAttn, B256, 0, stream>>>(qbuf, kbuf, vbuf, attn_bias, attnb);

  transpose64<<<gT, B256, 0, stream>>>(ow1, wtA, 1024, 1024);
  gemm_bt<64, 128, 1><<<gGemmN1k, B256, 0, stream>>>(
      attnb, wtA, ybf, nullptr, ob1, ybf, nullptr, 4096, 1024, 1024);

  // --- h = LN2(x + y) ---
  ln_add_kernel<<<4096, B256, 0, stream>>>(x, ybf, ln2_g, ln2_b, hbf);

  // --- FFN in two K-bands of 2048; accumulate fp32 into d_out ---
  for (int band = 0; band < 2; ++band) {
    // w1 cols [band*2048,+2048) -> wtA bf16 [2048,1024]
    transpose64<<<dim3(32, 16), B256, 0, stream>>>(w1 + band * 2048, wtA, 1024, 4096);
    // w2 rows [band*2048,+2048) -> wtB bf16 [1024,2048]
    transpose64<<<dim3(16, 32), B256, 0, stream>>>(w2 + (size_t)band * 2048 * 1024,
                                                   wtB, 2048, 1024);
    // fbuf = relu(hbf @ w1_band + b1_band)   [4096,2048] bf16
    gemm_bt<128, 128, 2><<<dim3(16, 32), B256, 0, stream>>>(
        hbf, wtA, fbuf, nullptr, b1 + band * 2048, nullptr, nullptr,
        4096, 2048, 1024);
    if (band == 0) {
      // d_out = fbuf @ w2_band + b2 + x + y   (fp32)
      gemm_bt<64, 128, 3><<<gGemmN1k, B256, 0, stream>>>(
          fbuf, wtB, nullptr, out32, b2, ybf, x, 4096, 1024, 2048);
    } else {
      // d_out += fbuf @ w2_band
      gemm_bt<64, 128, 4><<<gGemmN1k, B256, 0, stream>>>(
          fbuf, wtB, nullptr, out32, nullptr, nullptr, nullptr, 4096, 1024, 2048);
    }
  }
}

// Round 6
// 687.800 us; speedup vs baseline: 1.5110x; 1.5110x over previous
//
#include <hip/hip_runtime.h>
#include <stdint.h>

typedef unsigned short u16;
typedef __bf16 bf16x8 __attribute__((ext_vector_type(8)));
typedef float f32x4 __attribute__((ext_vector_type(4)));

#define LOG2E 1.4426950408889634f

__device__ __forceinline__ float bf2f(u16 a) {
  union { unsigned u; float f; } v; v.u = ((unsigned)a) << 16; return v.f;
}
__device__ __forceinline__ u16 f2bf(float f) {
  union { float f; unsigned u; } v; v.f = f;
  unsigned r = v.u + 0x7fffu + ((v.u >> 16) & 1u);
  return (u16)(r >> 16);
}
// async global->LDS, 16B/lane. LDS dest = wave-uniform base + lane*16.
__device__ __forceinline__ void gl_lds16(const void* g, void* l) {
  __builtin_amdgcn_global_load_lds(
      (const __attribute__((address_space(1))) uint32_t*)g,
      (__attribute__((address_space(3))) uint32_t*)l,
      16, 0, 0);
}

// ---------------------------------------------------------------------------
// GEMM: acc = A[M,K] @ Bt[N,K]^T  (bf16 in, fp32 accum), async LDS staging.
// BK=32, 4 waves 2x2, mfma 16x16x32 bf16.
// MODE: 0 bf16 C=acc | 1 bf16 C=acc+bias+res (o-proj, C may alias res)
//       2 bf16 C=relu(acc+bias) | 3 f32 C32=acc+bias+resx+bf2f(resbf)
//       4 f32 C32+=acc
// ---------------------------------------------------------------------------
template <int BM, int BN, int MODE>
__global__ __launch_bounds__(256) void gemm_bt(
    const u16* __restrict__ A, const u16* __restrict__ Bt,
    u16* Cbf, float* C32,
    const float* __restrict__ bias,
    const u16* resbf, const float* __restrict__ resx,
    int M, int N, int K)
{
  constexpr int MT = BM / 32, NT = BN / 32;
  constexpr int GA = (BM * 4) / 256, GB = (BN * 4) / 256;
  __shared__ u16 sA[BM * 32];
  __shared__ u16 sB[BN * 32];
  const int tid  = threadIdx.x;
  const int wave = tid >> 6, lane = tid & 63;
  const int quad = lane >> 4, l16 = lane & 15;
  const int wm = wave >> 1, wn = wave & 1;
  const int m0 = blockIdx.y * BM, n0 = blockIdx.x * BN;

  f32x4 acc[MT][NT] = {};

  for (int k0 = 0; k0 < K; k0 += 32) {
    __syncthreads();  // prev tile's LDS reads done
#pragma unroll
    for (int i = 0; i < GA; ++i) {
      int cb = i * 256 + wave * 64;   // wave-uniform LDS chunk base
      int c = cb + lane;
      int row = c >> 2, kc = c & 3;
      gl_lds16(A + (size_t)(m0 + row) * K + k0 + kc * 8, &sA[cb * 8]);
    }
#pragma unroll
    for (int i = 0; i < GB; ++i) {
      int cb = i * 256 + wave * 64;
      int c = cb + lane;
      int row = c >> 2, kc = c & 3;
      gl_lds16(Bt + (size_t)(n0 + row) * K + k0 + kc * 8, &sB[cb * 8]);
    }
    __syncthreads();  // barrier waitcnt drains vmcnt(0): staging complete

    bf16x8 fa[MT], fb[NT];
#pragma unroll
    for (int mt = 0; mt < MT; ++mt)
      fa[mt] = *(const bf16x8*)&sA[(wm * (BM / 2) + mt * 16 + l16) * 32 + quad * 8];
#pragma unroll
    for (int nt = 0; nt < NT; ++nt)
      fb[nt] = *(const bf16x8*)&sB[(wn * (BN / 2) + nt * 16 + l16) * 32 + quad * 8];
#pragma unroll
    for (int mt = 0; mt < MT; ++mt)
#pragma unroll
      for (int nt = 0; nt < NT; ++nt)
        acc[mt][nt] = __builtin_amdgcn_mfma_f32_16x16x32_bf16(
            fa[mt], fb[nt], acc[mt][nt], 0, 0, 0);
  }

  // epilogue: C layout col=lane&15, row=quad*4+reg
#pragma unroll
  for (int mt = 0; mt < MT; ++mt) {
#pragma unroll
    for (int nt = 0; nt < NT; ++nt) {
#pragma unroll
      for (int r = 0; r < 4; ++r) {
        int row = m0 + wm * (BM / 2) + mt * 16 + quad * 4 + r;
        int col = n0 + wn * (BN / 2) + nt * 16 + l16;
        size_t idx = (size_t)row * N + col;
        float v = acc[mt][nt][r];
        if constexpr (MODE == 0) {
          Cbf[idx] = f2bf(v);
        } else if constexpr (MODE == 1) {
          v += bias[col] + bf2f(resbf[idx]);
          Cbf[idx] = f2bf(v);
        } else if constexpr (MODE == 2) {
          v = fmaxf(v + bias[col], 0.f);
          Cbf[idx] = f2bf(v);
        } else if constexpr (MODE == 3) {
          v += bias[col] + resx[idx] + bf2f(resbf[idx]);
          C32[idx] = v;
        } else {
          C32[idx] = C32[idx] + v;
        }
      }
    }
  }
}

// ---------------------------------------------------------------------------
// 64x64-tiled transpose + fp32->bf16 cast: out[c][r] = (bf16)in[r][c].
// ---------------------------------------------------------------------------
__global__ __launch_bounds__(256) void transpose64(
    const float* __restrict__ in, u16* __restrict__ out, int R, int Cstride)
{
  __shared__ u16 tile[64][72];
  const int r0 = blockIdx.y * 64, c0 = blockIdx.x * 64;
  const int t = threadIdx.x;
  {
    const int lr = t >> 4, lc = (t & 15) * 4;
#pragma unroll
    for (int h = 0; h < 4; ++h) {
      int row = h * 16 + lr;
      float4 vd = *(const float4*)&in[(size_t)(r0 + row) * Cstride + c0 + lc];
      ushort4 ov;
      ov.x = f2bf(vd.x); ov.y = f2bf(vd.y); ov.z = f2bf(vd.z); ov.w = f2bf(vd.w);
      *(ushort4*)&tile[row][lc] = ov;
    }
  }
  __syncthreads();
  {
    const int lr = t >> 3, lv = t & 7;
#pragma unroll
    for (int h = 0; h < 2; ++h) {
      int orow = h * 32 + lr;
      u16 tmp[8];
#pragma unroll
      for (int j = 0; j < 8; ++j) tmp[j] = tile[lv * 8 + j][orow];
      *(uint4*)&out[(size_t)(c0 + orow) * R + r0 + lv * 8] = *(uint4*)tmp;
    }
  }
}

// ---------------------------------------------------------------------------
// V^T materialization: in = kvbuf v-half [b*1024+s][1024 + h*64 + d] (ld 2048)
// out vT[(b*16+h)*64 + d][s] (ld 1024). Grid (16 s-tiles, 64 bh).
// ---------------------------------------------------------------------------
__global__ __launch_bounds__(256) void vt_kernel(
    const u16* __restrict__ in, u16* __restrict__ out)
{
  __shared__ u16 tile[64][72];
  const int st = blockIdx.x, bh = blockIdx.y;
  const int b = bh >> 4, h = bh & 15;
  const int t = threadIdx.x;
  const int lr = t >> 3, lv = t & 7;
  const u16* src = in + ((size_t)b * 1024 + st * 64) * 2048 + 1024 + h * 64;
#pragma unroll
  for (int half = 0; half < 2; ++half) {
    int row = half * 32 + lr;  // s within tile
    uint4 vd = *(const uint4*)&src[(size_t)row * 2048 + lv * 8];
    *(uint4*)&tile[row][lv * 8] = vd;
  }
  __syncthreads();
  u16* dst = out + (size_t)bh * 64 * 1024 + st * 64;
#pragma unroll
  for (int half = 0; half < 2; ++half) {
    int orow = half * 32 + lr;  // d
    u16 tmp[8];
#pragma unroll
    for (int j = 0; j < 8; ++j) tmp[j] = tile[lv * 8 + j][orow];
    *(uint4*)&dst[(size_t)orow * 1024 + lv * 8] = *(uint4*)tmp;
  }
}

// ---------------------------------------------------------------------------
// LayerNorm over D=1024, fp32 in -> bf16 out.
// ---------------------------------------------------------------------------
__global__ __launch_bounds__(256) void ln_kernel(
    const float* __restrict__ x, const float* __restrict__ g,
    const float* __restrict__ b, u16* __restrict__ outbf)
{
  const int row = blockIdx.x, t = threadIdx.x;
  const int wave = t >> 6, lane = t & 63;
  float4 xv = *(const float4*)&x[(size_t)row * 1024 + t * 4];
  float v0 = xv.x, v1 = xv.y, v2 = xv.z, v3 = xv.w;
  float s = v0 + v1 + v2 + v3;
  float s2 = v0 * v0 + v1 * v1 + v2 * v2 + v3 * v3;
  for (int m = 1; m < 64; m <<= 1) { s += __shfl_xor(s, m); s2 += __shfl_xor(s2, m); }
  __shared__ float ps[4], pq[4];
  if (lane == 0) { ps[wave] = s; pq[wave] = s2; }
  __syncthreads();
  s = ps[0] + ps[1] + ps[2] + ps[3];
  s2 = pq[0] + pq[1] + pq[2] + pq[3];
  float mean = s * (1.f / 1024.f);
  float var = s2 * (1.f / 1024.f) - mean * mean;
  float rs = rsqrtf(var + 1e-5f);
  float4 gv = *(const float4*)&g[t * 4];
  float4 bv = *(const float4*)&b[t * 4];
  ushort4 ov;
  ov.x = f2bf((v0 - mean) * rs * gv.x + bv.x);
  ov.y = f2bf((v1 - mean) * rs * gv.y + bv.y);
  ov.z = f2bf((v2 - mean) * rs * gv.z + bv.z);
  ov.w = f2bf((v3 - mean) * rs * gv.w + bv.w);
  *(ushort4*)&outbf[(size_t)row * 1024 + t * 4] = ov;
}

// h = LN(x + y), x fp32, y bf16.
__global__ __launch_bounds__(256) void ln_add_kernel(
    const float* __restrict__ x, const u16* __restrict__ ybf,
    const float* __restrict__ g, const float* __restrict__ b,
    u16* __restrict__ hbf)
{
  const int row = blockIdx.x, t = threadIdx.x;
  const int wave = t >> 6, lane = t & 63;
  float4 xv = *(const float4*)&x[(size_t)row * 1024 + t * 4];
  ushort4 yv = *(const ushort4*)&ybf[(size_t)row * 1024 + t * 4];
  float v0 = xv.x + bf2f(yv.x), v1 = xv.y + bf2f(yv.y);
  float v2 = xv.z + bf2f(yv.z), v3 = xv.w + bf2f(yv.w);
  float s = v0 + v1 + v2 + v3;
  float s2 = v0 * v0 + v1 * v1 + v2 * v2 + v3 * v3;
  for (int m = 1; m < 64; m <<= 1) { s += __shfl_xor(s, m); s2 += __shfl_xor(s2, m); }
  __shared__ float ps[4], pq[4];
  if (lane == 0) { ps[wave] = s; pq[wave] = s2; }
  __syncthreads();
  s = ps[0] + ps[1] + ps[2] + ps[3];
  s2 = pq[0] + pq[1] + pq[2] + pq[3];
  float mean = s * (1.f / 1024.f);
  float var = s2 * (1.f / 1024.f) - mean * mean;
  float rs = rsqrtf(var + 1e-5f);
  float4 gv = *(const float4*)&g[t * 4];
  float4 bv = *(const float4*)&b[t * 4];
  ushort4 ov;
  ov.x = f2bf((v0 - mean) * rs * gv.x + bv.x);
  ov.y = f2bf((v1 - mean) * rs * gv.y + bv.y);
  ov.z = f2bf((v2 - mean) * rs * gv.z + bv.z);
  ov.w = f2bf((v3 - mean) * rs * gv.w + bv.w);
  *(ushort4*)&hbf[(size_t)row * 1024 + t * 4] = ov;
}

// ---------------------------------------------------------------------------
// Flash-style cross-attention v2. Block = (64-q-tile, head, batch).
// K from kvbuf (ld 2048), V from pre-transposed vT (conflict-free staging).
// All staging via async global_load_lds. Wave w owns q-rows [w*16, w*16+16).
// ---------------------------------------------------------------------------
__global__ __launch_bounds__(256) void attn_kernel(
    const u16* __restrict__ Q,   // [b*1024+s1][1024], head offset h*64
    const u16* __restrict__ K,   // kvbuf [b*1024+s2][2048], head offset h*64
    const u16* __restrict__ Vt,  // [(b*16+h)*64+d][1024]
    const int* __restrict__ mask,
    u16* __restrict__ O)         // [b*1024+s1][1024]
{
  __shared__ u16 sQ[64 * 64], sK[64 * 64], sVt[64 * 64], sP[64 * 64];
  __shared__ int smaski[64];
  const int qt = blockIdx.x, h = blockIdx.y, b = blockIdx.z;
  const int t = threadIdx.x;
  const int wave = t >> 6, lane = t & 63;
  const int quad = lane >> 4, l16 = lane & 15;
  const u16* Qb = Q + (size_t)b * 1024 * 1024 + (size_t)qt * 64 * 1024 + h * 64;
  const u16* Kb = K + (size_t)b * 1024 * 2048 + h * 64;
  const u16* Vb = Vt + (size_t)(b * 16 + h) * 64 * 1024;

  // stage Q [64 s1][64 dk] async
#pragma unroll
  for (int i = 0; i < 2; ++i) {
    int cb = i * 256 + wave * 64;
    int c = cb + lane;
    int row = c >> 3, cc = c & 7;
    gl_lds16(Qb + (size_t)row * 1024 + cc * 8, &sQ[cb * 8]);
  }

  float m_[4], l_[4];
  f32x4 accO[4] = {};
#pragma unroll
  for (int r = 0; r < 4; ++r) { m_[r] = -1e30f; l_[r] = 0.f; }

  for (int j = 0; j < 16; ++j) {
    __syncthreads();  // prev iter's LDS reads done
    // sK [64 s2][64 dk], rows from ld-2048 kvbuf
#pragma unroll
    for (int i = 0; i < 2; ++i) {
      int cb = i * 256 + wave * 64;
      int c = cb + lane;
      int row = c >> 3, cc = c & 7;
      gl_lds16(Kb + (size_t)(j * 64 + row) * 2048 + cc * 8, &sK[cb * 8]);
    }
    // sVt [64 d][64 s2] straight rows from vT — conflict-free
#pragma unroll
    for (int i = 0; i < 2; ++i) {
      int cb = i * 256 + wave * 64;
      int c = cb + lane;
      int row = c >> 3, cc = c & 7;
      gl_lds16(Vb + (size_t)row * 1024 + j * 64 + cc * 8, &sVt[cb * 8]);
    }
    if (t < 64) smaski[t] = mask[b * 1024 + j * 64 + t];
    __syncthreads();  // drains vmcnt: sQ(j=0)/sK/sVt staged, smaski visible

    // S = Q K^T : this wave's 16 q-rows x 64 s2-cols
    f32x4 accS[4] = {};
#pragma unroll
    for (int ks = 0; ks < 2; ++ks) {
      bf16x8 aq = *(const bf16x8*)&sQ[(wave * 16 + l16) * 64 + ks * 32 + quad * 8];
#pragma unroll
      for (int nt = 0; nt < 4; ++nt) {
        bf16x8 bk = *(const bf16x8*)&sK[(nt * 16 + l16) * 64 + ks * 32 + quad * 8];
        accS[nt] = __builtin_amdgcn_mfma_f32_16x16x32_bf16(aq, bk, accS[nt], 0, 0, 0);
      }
    }
    // online softmax per row (row = wave*16 + quad*4 + r)
#pragma unroll
    for (int r = 0; r < 4; ++r) {
      float vals[4];
#pragma unroll
      for (int nt = 0; nt < 4; ++nt) {
        float sv = accS[nt][r] * 0.125f;
        vals[nt] = (smaski[nt * 16 + l16] == 0) ? -1e9f : sv;
      }
      float cm = fmaxf(fmaxf(vals[0], vals[1]), fmaxf(vals[2], vals[3]));
      for (int sh = 1; sh < 16; sh <<= 1) cm = fmaxf(cm, __shfl_xor(cm, sh));
      float nm = fmaxf(m_[r], cm);
      float alpha = exp2f((m_[r] - nm) * LOG2E);
      float rsum = 0.f;
#pragma unroll
      for (int nt = 0; nt < 4; ++nt) {
        float p = exp2f((vals[nt] - nm) * LOG2E);
        rsum += p;
        sP[(wave * 16 + quad * 4 + r) * 64 + nt * 16 + l16] = f2bf(p);
      }
      for (int sh = 1; sh < 16; sh <<= 1) rsum += __shfl_xor(rsum, sh);
      l_[r] = l_[r] * alpha + rsum;
      m_[r] = nm;
#pragma unroll
      for (int nt2 = 0; nt2 < 4; ++nt2) accO[nt2][r] *= alpha;
    }
    __syncthreads();  // sP ready
    // O += P @ V
#pragma unroll
    for (int ks = 0; ks < 2; ++ks) {
      bf16x8 ap = *(const bf16x8*)&sP[(wave * 16 + l16) * 64 + ks * 32 + quad * 8];
#pragma unroll
      for (int nt2 = 0; nt2 < 4; ++nt2) {
        bf16x8 bvv = *(const bf16x8*)&sVt[(nt2 * 16 + l16) * 64 + ks * 32 + quad * 8];
        accO[nt2] = __builtin_amdgcn_mfma_f32_16x16x32_bf16(ap, bvv, accO[nt2], 0, 0, 0);
      }
    }
  }

  u16* Ob = O + (size_t)b * 1024 * 1024 + (size_t)qt * 64 * 1024 + h * 64;
#pragma unroll
  for (int r = 0; r < 4; ++r) {
    float inv = 1.f / l_[r];
    int row = wave * 16 + quad * 4 + r;
#pragma unroll
    for (int nt2 = 0; nt2 < 4; ++nt2)
      Ob[(size_t)row * 1024 + nt2 * 16 + l16] = f2bf(accO[nt2][r] * inv);
  }
}

// ---------------------------------------------------------------------------
extern "C" void kernel_launch(void* const* d_in, const int* in_sizes, int n_in,
                              void* d_out, int out_size, void* d_ws, size_t ws_size,
                              hipStream_t stream)
{
  const float* x   = (const float*)d_in[0];
  const float* kv  = (const float*)d_in[1];
  const int* attn_bias = (const int*)d_in[2];
  const float* ln1_g = (const float*)d_in[3];
  const float* ln1_b = (const float*)d_in[4];
  const float* qw0 = (const float*)d_in[5];
  const float* kw0 = (const float*)d_in[6];
  const float* vw0 = (const float*)d_in[7];
  const float* ow0 = (const float*)d_in[8];
  const float* ob0 = (const float*)d_in[9];
  const float* qw1 = (const float*)d_in[10];
  const float* kw1 = (const float*)d_in[11];
  const float* vw1 = (const float*)d_in[12];
  const float* ow1 = (const float*)d_in[13];
  const float* ob1 = (const float*)d_in[14];
  const float* ln2_g = (const float*)d_in[15];
  const float* ln2_b = (const float*)d_in[16];
  const float* w1 = (const float*)d_in[17];
  const float* b1 = (const float*)d_in[18];
  const float* w2 = (const float*)d_in[19];
  const float* b2 = (const float*)d_in[20];

  // ---- workspace: 48 MB peak (proven safe), d_out doubles as scratch ----
  char* ws = (char*)d_ws;
  const size_t MB = 1u << 20;
  u16* Wkv   = (u16*)(ws + 0 * MB);    // stacked kv weight-T [2048,1024] 4MB
  u16* Wsm   = (u16*)(ws + 4 * MB);    // q/o weight-T [1024,1024] 2MB (serial)
  u16* wtA   = (u16*)(ws + 0 * MB);    // FFN band w1-T [2048,1024] 4MB
  u16* wtB   = (u16*)(ws + 4 * MB);    // FFN band w2-T [1024,2048] 4MB
  u16* ybf   = (u16*)(ws + 8 * MB);    // residual y bf16 8MB
  u16* kvnbf = (u16*)(ws + 16 * MB);   // LN1(kv) 8MB; hbf aliases later
  u16* qbuf  = (u16*)(ws + 24 * MB);   // q bf16 8MB
  u16* kvbuf = (u16*)(ws + 32 * MB);   // [4096,2048] k|v 16MB; fbuf aliases
  u16* hbf   = kvnbf;
  u16* fbuf  = kvbuf;                  // [4096,2048] bf16 16MB
  u16* attnb = (u16*)d_out;                      // lower 8MB of d_out
  u16* vT    = (u16*)((char*)d_out + 8 * MB);    // upper 8MB of d_out
  float* out32 = (float*)d_out;

  const dim3 B256(256);
  const dim3 gT(16, 16);         // 1024x1024 weight transpose
  const dim3 gGemmN1k(8, 64);    // <64,128>  N=1024
  const dim3 gGemm2k(16, 32);    // <128,128> N=2048
  const dim3 gVt(16, 64);
  const dim3 gAttn(16, 16, 4);

  // --- LN1 ---
  ln_kernel<<<4096, B256, 0, stream>>>(x,  ln1_g, ln1_b, ybf);
  ln_kernel<<<4096, B256, 0, stream>>>(kv, ln1_g, ln1_b, kvnbf);

  for (int layer = 0; layer < 2; ++layer) {
    const float* qw = layer ? qw1 : qw0;
    const float* kw = layer ? kw1 : kw0;
    const float* vw = layer ? vw1 : vw0;
    const float* ow = layer ? ow1 : ow0;
    const float* ob = layer ? ob1 : ob0;

    // fused k|v projection: Wkv = [kw^T ; vw^T] (2048x1024)
    transpose64<<<gT, B256, 0, stream>>>(kw, Wkv, 1024, 1024);
    transpose64<<<gT, B256, 0, stream>>>(vw, Wkv + 1024 * 1024, 1024, 1024);
    gemm_bt<128, 128, 0><<<gGemm2k, B256, 0, stream>>>(
        kvnbf, Wkv, kvbuf, nullptr, nullptr, nullptr, nullptr, 4096, 2048, 1024);
    // q projection
    transpose64<<<gT, B256, 0, stream>>>(qw, Wsm, 1024, 1024);
    gemm_bt<64, 128, 0><<<gGemmN1k, B256, 0, stream>>>(
        ybf, Wsm, qbuf, nullptr, nullptr, nullptr, nullptr, 4096, 1024, 1024);
    // V^T materialization from kvbuf v-half
    vt_kernel<<<gVt, B256, 0, stream>>>(kvbuf, vT);

    attn_kernel<<<gAttn, B256, 0, stream>>>(qbuf, kvbuf, vT, attn_bias, attnb);

    // y = attn_out @ ow + ob + y
    transpose64<<<gT, B256, 0, stream>>>(ow, Wsm, 1024, 1024);
    gemm_bt<64, 128, 1><<<gGemmN1k, B256, 0, stream>>>(
        attnb, Wsm, ybf, nullptr, ob, ybf, nullptr, 4096, 1024, 1024);
  }

  // --- h = LN2(x + y) ---
  ln_add_kernel<<<4096, B256, 0, stream>>>(x, ybf, ln2_g, ln2_b, hbf);

  // --- FFN in two K-bands of 2048; fp32 accumulate into d_out ---
  for (int band = 0; band < 2; ++band) {
    transpose64<<<dim3(32, 16), B256, 0, stream>>>(w1 + band * 2048, wtA, 1024, 4096);
    transpose64<<<dim3(16, 32), B256, 0, stream>>>(w2 + (size_t)band * 2048 * 1024,
                                                   wtB, 2048, 1024);
    gemm_bt<128, 128, 2><<<gGemm2k, B256, 0, stream>>>(
        hbf, wtA, fbuf, nullptr, b1 + band * 2048, nullptr, nullptr,
        4096, 2048, 1024);
    if (band == 0) {
      gemm_bt<64, 128, 3><<<gGemmN1k, B256, 0, stream>>>(
          fbuf, wtB, nullptr, out32, b2, ybf, x, 4096, 1024, 2048);
    } else {
      gemm_bt<64, 128, 4><<<gGemmN1k, B256, 0, stream>>>(
          fbuf, wtB, nullptr, out32, nullptr, nullptr, nullptr, 4096, 1024, 2048);
    }
  }
}